// Round 1
// baseline (287.049 us; speedup 1.0000x reference)
//
#include <hip/hip_runtime.h>
#include <stdint.h>

// PointPillars constants (KITTI config)
#define GRID_X 432
#define GRID_Y 496
#define NB 4
#define NPTS 32
#define NC 64
#define NSLOTS 64
#define CELLS (GRID_Y * GRID_X)   // 214272 per batch (y-major, x fastest)

constexpr float VXc = 0.16f, VYc = 0.16f;
constexpr float X_OFFSET = 0.08f, Y_OFFSET = -39.60f, Z_CONST = -1.0f;
constexpr float BN_EPS = 1e-3f;

// Kernel A: per-pillar feature max/min per channel + BN stat partials + inverse map
__global__ __launch_bounds__(256) void pillar_stats_kernel(
    const float* __restrict__ pillars, const float* __restrict__ W,
    const int* __restrict__ cx, const int* __restrict__ cy,
    const int* __restrict__ cb, const int* __restrict__ npoints,
    float* __restrict__ vmax, float* __restrict__ vmin, int* __restrict__ map,
    double* __restrict__ dsum, double* __restrict__ dsq, int P)
{
    __shared__ float4 pts[4][NPTS];      // 2 KB: 4 pillars x 32 points
    __shared__ float pinfo[4][4];        // mx, my, mz, npf per pillar
    __shared__ float ssum[4][NC], ssq[4][NC];

    const int tid = threadIdx.x;
    const int p0 = blockIdx.x * 4;

    // Phase A: stage points (coalesced float4) + per-pillar xyz sum over ALL 32 points
    if (tid < 128) {
        int pl = tid >> 5, n = tid & 31;
        int p = p0 + pl;
        float4 v = make_float4(0.f, 0.f, 0.f, 0.f);
        if (p < P) v = ((const float4*)pillars)[(size_t)p * NPTS + n];
        pts[pl][n] = v;
        float sx = v.x, sy = v.y, sz = v.z;
        #pragma unroll
        for (int m = 16; m >= 1; m >>= 1) {
            sx += __shfl_xor(sx, m, 32);
            sy += __shfl_xor(sy, m, 32);
            sz += __shfl_xor(sz, m, 32);
        }
        if (n == 0 && p < P) {
            float npf = (float)npoints[p];
            pinfo[pl][0] = sx / npf;
            pinfo[pl][1] = sy / npf;
            pinfo[pl][2] = sz / npf;
            pinfo[pl][3] = npf;
        }
    }
    // inverse map: cell -> pillar index
    if (tid >= 128 && tid < 132) {
        int p = p0 + (tid - 128);
        if (p < P) {
            int b = cb[p];
            map[(size_t)b * CELLS + (size_t)cy[p] * GRID_X + cx[p]] = p;
        }
    }
    __syncthreads();

    // Phase B: wave per pillar, lane = channel
    const int pl = tid >> 6, c = tid & 63;
    const int p = p0 + pl;
    float ssu = 0.f, sq2 = 0.f;
    if (p < P) {
        const float* w = W + c * 10;
        float w0 = w[0], w1 = w[1], w2 = w[2], w3 = w[3], w4 = w[4];
        float w5 = w[5], w6 = w[6], w7 = w[7], w8 = w[8], w9 = w[9];
        float Aw = w0 + w4 + w7;
        float Bw = w1 + w5 + w8;
        float Cw = w2 + w6;
        float Dw = w3;
        float cxo = cx[p] * VXc + X_OFFSET;
        float cyo = cy[p] * VYc + Y_OFFSET;
        float mx = pinfo[pl][0], my = pinfo[pl][1], mz = pinfo[pl][2];
        int np = (int)pinfo[pl][3];
        float E = -cxo * (w0 + w7) - cyo * (w1 + w8)
                  - mx * w4 - my * w5 - mz * w6 + Z_CONST * w9;
        float smax = -1e30f, smin = 1e30f;
        #pragma unroll
        for (int n = 0; n < NPTS; ++n) {
            float4 pt = pts[pl][n];           // wave-uniform addr -> LDS broadcast
            float v = E;
            v = fmaf(pt.x, Aw, v);
            v = fmaf(pt.y, Bw, v);
            v = fmaf(pt.z, Cw, v);
            v = fmaf(pt.w, Dw, v);
            v = (n < np) ? v : 0.0f;          // masked points -> exactly 0 (matches ref)
            smax = fmaxf(smax, v);
            smin = fminf(smin, v);
            ssu += v;
            sq2 = fmaf(v, v, sq2);
        }
        vmax[(size_t)p * NC + c] = smax;
        vmin[(size_t)p * NC + c] = smin;
    }
    ssum[pl][c] = ssu;
    ssq[pl][c]  = sq2;
    __syncthreads();
    if (tid < NC) {
        float s = ssum[0][tid] + ssum[1][tid] + ssum[2][tid] + ssum[3][tid];
        float q = ssq[0][tid]  + ssq[1][tid]  + ssq[2][tid]  + ssq[3][tid];
        int slot = blockIdx.x & (NSLOTS - 1);
        atomicAdd(&dsum[slot * NC + tid], (double)s);
        atomicAdd(&dsq[slot * NC + tid],  (double)q);
    }
}

// Kernel B: fold slot accumulators -> BN scale/shift per channel
__global__ void bn_params_kernel(const double* __restrict__ dsum,
                                 const double* __restrict__ dsq,
                                 const float* __restrict__ gamma,
                                 const float* __restrict__ beta,
                                 float* __restrict__ st, int P)
{
    int c = threadIdx.x;
    if (c < NC) {
        double s = 0.0, q = 0.0;
        for (int i = 0; i < NSLOTS; ++i) { s += dsum[i * NC + c]; q += dsq[i * NC + c]; }
        double cnt = (double)P * NPTS;
        double mu = s / cnt;
        double var = q / cnt - mu * mu;
        float scale = gamma[c] * (float)(1.0 / sqrt(var + (double)BN_EPS));
        float shift = beta[c] - (float)mu * scale;
        st[c] = scale;
        st[NC + c] = shift;
    }
}

// Kernel C: gather-style dense output, channel-outer for coalesced writes
__global__ __launch_bounds__(256) void scatter_out_kernel(
    const int* __restrict__ map, const float* __restrict__ vmax,
    const float* __restrict__ vmin, const float* __restrict__ st,
    float* __restrict__ out)
{
    const int q = blockIdx.x * 256 + threadIdx.x;   // cell within batch, x fastest
    const int b = blockIdx.y;
    const int m = map[(size_t)b * CELLS + q];
    float* ob = out + (size_t)b * NC * CELLS + q;
    #pragma unroll 8
    for (int c = 0; c < NC; ++c) {
        float r = 0.0f;
        if (m >= 0) {
            float s = st[c], t = st[NC + c];
            float v = (s >= 0.0f) ? vmax[(size_t)m * NC + c] : vmin[(size_t)m * NC + c];
            r = fmaxf(fmaf(s, v, t), 0.0f);
        }
        ob[(size_t)c * CELLS] = r;
    }
}

extern "C" void kernel_launch(void* const* d_in, const int* in_sizes, int n_in,
                              void* d_out, int out_size, void* d_ws, size_t ws_size,
                              hipStream_t stream) {
    const float* pillars = (const float*)d_in[0];
    const float* W       = (const float*)d_in[1];
    const float* gamma   = (const float*)d_in[2];
    const float* beta    = (const float*)d_in[3];
    const int*   cx      = (const int*)d_in[4];
    const int*   cy      = (const int*)d_in[5];
    const int*   cb      = (const int*)d_in[6];
    const int*   np      = (const int*)d_in[7];
    const int P = in_sizes[4];      // 48000

    // workspace carve-up (~28 MB)
    char* ws = (char*)d_ws;
    float* vmax = (float*)ws;
    float* vmin = vmax + (size_t)P * NC;
    int*   map  = (int*)(vmin + (size_t)P * NC);
    size_t mapN = (size_t)NB * CELLS;
    double* dsum = (double*)(((uintptr_t)(map + mapN) + 255) & ~(uintptr_t)255);
    double* dsq  = dsum + NSLOTS * NC;
    float*  st   = (float*)(dsq + NSLOTS * NC);

    hipMemsetAsync(map, 0xFF, mapN * sizeof(int), stream);                 // -1 = empty
    hipMemsetAsync(dsum, 0, (size_t)NSLOTS * NC * 2 * sizeof(double), stream);

    pillar_stats_kernel<<<(P + 3) / 4, 256, 0, stream>>>(
        pillars, W, cx, cy, cb, np, vmax, vmin, map, dsum, dsq, P);
    bn_params_kernel<<<1, 64, 0, stream>>>(dsum, dsq, gamma, beta, st, P);
    scatter_out_kernel<<<dim3(CELLS / 256, NB), 256, 0, stream>>>(
        map, vmax, vmin, st, (float*)d_out);
}